// Round 2
// baseline (10.494 us; speedup 1.0000x reference)
//
#include <hip/hip_runtime.h>
#include <hip/hip_bf16.h>

// Problem constants (match the reference)
#define BB 128   // batch
#define LL 128   // seq len
// VOCAB_P1 = 1024 (unused: identity embedding collapses to token equality)

// out[b][q][c] = (qry[b][q] == cnd[b][c] && qry[b][q] > 0) ? 1.0f : 0.0f
// (equality with qry>0 implies cnd>0, so one validity check suffices)

#define QROWS 16                     // q-rows per block
#define BLOCKS_PER_B (LL / QROWS)    // 8
#define F4_PER_ROW (LL / 4)          // 32 float4 per c-row

__global__ __launch_bounds__(256)
void align_binary_kernel(const int* __restrict__ qry,
                         const int4* __restrict__ cnd4,
                         float4* __restrict__ out) {
    const int blk = blockIdx.x;
    const int b  = blk >> 3;              // blk / BLOCKS_PER_B
    const int q0 = (blk & 7) * QROWS;     // (blk % BLOCKS_PER_B) * QROWS
    const int t  = threadIdx.x;

    const int q  = t >> 5;                // 0..7  (row within half-tile)
    const int c4 = t & 31;                // float4 column

    // Issue all loads up front; inputs are L2-resident (128 KB total).
    // cnd int4 is shared by both output rows this thread writes.
    const int4 cv  = cnd4[b * F4_PER_ROW + c4];
    const int  qv0 = qry[b * LL + q0 + q];        // row q0+q
    const int  qv1 = qry[b * LL + q0 + 8 + q];    // row q0+8+q

    float4 r0, r1;
    {
        const bool v = (qv0 > 0);
        r0.x = (v && cv.x == qv0) ? 1.0f : 0.0f;
        r0.y = (v && cv.y == qv0) ? 1.0f : 0.0f;
        r0.z = (v && cv.z == qv0) ? 1.0f : 0.0f;
        r0.w = (v && cv.w == qv0) ? 1.0f : 0.0f;
    }
    {
        const bool v = (qv1 > 0);
        r1.x = (v && cv.x == qv1) ? 1.0f : 0.0f;
        r1.y = (v && cv.y == qv1) ? 1.0f : 0.0f;
        r1.z = (v && cv.z == qv1) ? 1.0f : 0.0f;
        r1.w = (v && cv.w == qv1) ? 1.0f : 0.0f;
    }

    float4* base = out + ((size_t)(b * LL + q0 + q)) * F4_PER_ROW + c4;
    base[0] = r0;
    base[8 * F4_PER_ROW] = r1;   // row +8
}

extern "C" void kernel_launch(void* const* d_in, const int* in_sizes, int n_in,
                              void* d_out, int out_size, void* d_ws, size_t ws_size,
                              hipStream_t stream) {
    // setup_inputs order: emb_weight (f32, unused), qry_lkup (i32), cnd_lkup (i32)
    const int* qry = (const int*)d_in[1];
    const int4* cnd4 = (const int4*)d_in[2];
    float4* out = (float4*)d_out;

    const int grid = BB * BLOCKS_PER_B;  // 1024 blocks
    align_binary_kernel<<<grid, 256, 0, stream>>>(qry, cnd4, out);
}